// Round 11
// baseline (61.719 us; speedup 1.0000x reference)
//
#include <hip/hip_runtime.h>

typedef unsigned int uint;
typedef unsigned short ushort_t;
typedef __attribute__((ext_vector_type(8))) short short8v;   // 8 bf16 (4 VGPRs)
typedef __attribute__((ext_vector_type(4))) float f32x4;

#define BATCH 8
#define HH 128
#define WW 128
#define CC 64
#define NPIX (BATCH * HH * WW)   // 131072
#define KK 9
#define BN_EPS 1e-3f

__device__ __forceinline__ uint f2bfbits(float f) {
    uint u = __float_as_uint(f);
    return (u + 0x7fffu + ((u >> 16) & 1u)) >> 16;   // RNE
}

// ---- setup: w1 -> bf16 [d][c]; w2 -> bf16 transposed [k][d] (16 rows, pad 0); fold BN ----
__global__ void setup_kernel(const float* __restrict__ w1,
                             const float* __restrict__ b1,
                             const float* __restrict__ gamma,
                             const float* __restrict__ beta,
                             const float* __restrict__ bn_mean,
                             const float* __restrict__ bn_var,
                             const float* __restrict__ w2,
                             const float* __restrict__ b2,
                             ushort_t* __restrict__ w1b,    // [64][64] bf16: w1b[d][c] = w1[c][d]
                             ushort_t* __restrict__ w2bT,   // [16][64] bf16: w2bT[k][d] = w2[d][k]
                             float* __restrict__ scalef,    // [64]
                             float* __restrict__ biasf,     // [64]
                             float* __restrict__ b2f)       // [9]
{
    int t = blockIdx.x * blockDim.x + threadIdx.x;
    int nt = gridDim.x * blockDim.x;
    for (int idx = t; idx < CC * CC; idx += nt) {
        int d = idx >> 6, c = idx & 63;
        w1b[idx] = (ushort_t)f2bfbits(w1[c * CC + d]);
    }
    for (int idx = t; idx < 16 * CC; idx += nt) {
        int k = idx >> 6, d = idx & 63;
        w2bT[idx] = (k < KK) ? (ushort_t)f2bfbits(w2[d * KK + k]) : (ushort_t)0;
    }
    if (t < CC) {
        float s = gamma[t] * rsqrtf(bn_var[t] + BN_EPS);
        scalef[t] = s;
        biasf[t] = (b1[t] - bn_mean[t]) * s + beta[t];
    }
    if (t < KK) b2f[t] = b2[t];
}

// ---- K1: kern generation. dense stage -> ONE barrier -> wave-autonomous MFMA ----
__global__ __launch_bounds__(256) void kern_gen(
    const float* __restrict__ x,
    const ushort_t* __restrict__ w1b,
    const ushort_t* __restrict__ w2bT,
    const float* __restrict__ scalef,
    const float* __restrict__ biasf,
    const float* __restrict__ b2f,
    float* __restrict__ kout)    // [NPIX][9]
{
    __shared__ ushort_t xB[64][72];        // staged x tile (bf16), 9.2 KB
    __shared__ ushort_t hL[4][16][72];     // per-wave h (bf16), 9.2 KB
    __shared__ float    kS[4][16 * KK];    // per-wave kern (packed), 2.3 KB

    const int t = threadIdx.x;
    const int w = __builtin_amdgcn_readfirstlane(t >> 6);
    const int l = t & 63;
    const int lq = l >> 4, lr = l & 15;
    int bid = blockIdx.x;
    bid = (bid & 7) * 256 + (bid >> 3);    // XCD swizzle (2048 = 8*256, bijective)
    const int p0 = bid * 64;

    // ---- phase 0: DENSE stage x -> bf16 LDS (contiguous 1KB per instruction) ----
#pragma unroll
    for (int r = 0; r < 4; ++r) {
        int idx = t + r * 256;
        int px = idx >> 4, c4 = idx & 15;
        float4 v = *(const float4*)(x + (size_t)(p0 + px) * CC + c4 * 4);
        uint2 pk;
        pk.x = f2bfbits(v.x) | (f2bfbits(v.y) << 16);
        pk.y = f2bfbits(v.z) | (f2bfbits(v.w) << 16);
        *(uint2*)(&xB[px][c4 * 4]) = pk;
    }
    __syncthreads();   // the ONLY barrier

    // ---- GEMM1: wave w owns px [w*16, w*16+16); all 64 d. A from LDS (r6 recipe) ----
    short8v af[2];
#pragma unroll
    for (int ks = 0; ks < 2; ++ks)
        af[ks] = *(const short8v*)(&xB[w * 16 + lr][ks * 32 + lq * 8]);

    f32x4 acc[4];
#pragma unroll
    for (int n = 0; n < 4; ++n) acc[n] = (f32x4){0.f, 0.f, 0.f, 0.f};
#pragma unroll
    for (int ks = 0; ks < 2; ++ks)
#pragma unroll
        for (int n = 0; n < 4; ++n) {
            short8v bf = *(const short8v*)(w1b + (n * 16 + lr) * CC + ks * 32 + lq * 8);
            acc[n] = __builtin_amdgcn_mfma_f32_16x16x32_bf16(af[ks], bf, acc[n], 0, 0, 0);
        }

    // ---- epilogue: BN+ReLU -> bf16 -> hL (C layout: row=px=lq*4+r, col=d=n*16+lr) ----
#pragma unroll
    for (int n = 0; n < 4; ++n) {
        const int d = n * 16 + lr;
        const float s = scalef[d], bb = biasf[d];
#pragma unroll
        for (int r = 0; r < 4; ++r) {
            float hv = fmaxf(fmaf(acc[n][r], s, bb), 0.f);
            hL[w][lq * 4 + r][d] = (ushort_t)f2bfbits(hv);
        }
    }
    // same-wave LDS handoff (compiler lgkmcnt; r9-proven)

    // ---- GEMM2: kern = h @ w2 + b2 via MFMA (M=16px, N=16 pad, K=64; r9 recipe) ----
    f32x4 acc2 = (f32x4){0.f, 0.f, 0.f, 0.f};
#pragma unroll
    for (int ks = 0; ks < 2; ++ks) {
        short8v a2  = *(const short8v*)(&hL[w][lr][ks * 32 + lq * 8]);
        short8v b2v = *(const short8v*)(w2bT + lr * CC + ks * 32 + lq * 8);
        acc2 = __builtin_amdgcn_mfma_f32_16x16x32_bf16(a2, b2v, acc2, 0, 0, 0);
    }
    // C2: lane holds kern[px=lq*4+r][k=lr] (lr<9 valid) -> packed kS
    if (lr < KK) {
        const float bk = b2f[lr];
#pragma unroll
        for (int r = 0; r < 4; ++r)
            kS[w][(lq * 4 + r) * KK + lr] = acc2[r] + bk;
    }
    // same-wave handoff, then dense drain: 36 contiguous float4 per wave (576 B)
    {
        float* kbase = kout + (size_t)(p0 + w * 16) * KK;
        if (l < 36) {
            f32x4 v = *(f32x4*)(&kS[w][l * 4]);
            *(f32x4*)(kbase + l * 4) = v;
        }
    }
}

// ---- K2: involution (r5/r10-proven). thread = (pixel, 16-ch quarter). plain stores ----
__global__ __launch_bounds__(256) void invol2(
    const float* __restrict__ x,
    const float* __restrict__ kern_in,   // [NPIX][9]
    float* __restrict__ out)             // [NPIX][64]
{
    int bid = blockIdx.x;
    bid = (bid & 7) * 256 + (bid >> 3);  // XCD swizzle (2048 = 8*256, bijective)
    int T = bid * 256 + threadIdx.x;
    int p = T >> 2;
    int c0 = (T & 3) * 16;
    int b = p >> 14;
    int i = (p >> 7) & 127;
    int j = p & 127;

    float kern[KK];
    const float* kr = kern_in + (size_t)p * KK;
#pragma unroll
    for (int k = 0; k < KK; ++k) kern[k] = kr[k];

    float acc[16];
#pragma unroll
    for (int e = 0; e < 16; ++e) acc[e] = 0.f;

#pragma unroll
    for (int tap = 0; tap < KK; ++tap) {
        const int di = tap / 3 - 1, dj = tap % 3 - 1;
        int ii = i + di, jj = j + dj;
        bool valid = (ii >= 0) && (ii < HH) && (jj >= 0) && (jj < WW);
        float kv = valid ? kern[tap] : 0.f;
        int iic = min(max(ii, 0), HH - 1);
        int jjc = min(max(jj, 0), WW - 1);
        const float4* np = (const float4*)(x + (((size_t)b * HH + iic) * WW + jjc) * CC + c0);
#pragma unroll
        for (int f = 0; f < 4; ++f) {
            float4 v = np[f];
            acc[f * 4 + 0] = fmaf(kv, v.x, acc[f * 4 + 0]);
            acc[f * 4 + 1] = fmaf(kv, v.y, acc[f * 4 + 1]);
            acc[f * 4 + 2] = fmaf(kv, v.z, acc[f * 4 + 2]);
            acc[f * 4 + 3] = fmaf(kv, v.w, acc[f * 4 + 3]);
        }
    }

    float4* op = (float4*)(out + (size_t)p * CC + c0);
#pragma unroll
    for (int f = 0; f < 4; ++f)
        op[f] = make_float4(acc[f * 4 + 0], acc[f * 4 + 1], acc[f * 4 + 2], acc[f * 4 + 3]);
}

extern "C" void kernel_launch(void* const* d_in, const int* in_sizes, int n_in,
                              void* d_out, int out_size, void* d_ws, size_t ws_size,
                              hipStream_t stream) {
    const float* x       = (const float*)d_in[0];
    const float* w1      = (const float*)d_in[1];
    const float* b1      = (const float*)d_in[2];
    const float* gamma   = (const float*)d_in[3];
    const float* beta    = (const float*)d_in[4];
    const float* bn_mean = (const float*)d_in[5];
    const float* bn_var  = (const float*)d_in[6];
    const float* w2      = (const float*)d_in[7];
    const float* b2      = (const float*)d_in[8];

    ushort_t* w1b  = (ushort_t*)d_ws;                // 4096 ush = 8192 B
    ushort_t* w2bT = w1b + CC * CC;                  // 1024 ush = 2048 B
    float* scalef  = (float*)(w2bT + 16 * CC);       // 64
    float* biasf   = scalef + CC;                    // 64
    float* b2f     = biasf + CC;                     // 9

    float* out  = (float*)d_out;
    float* kout = out + (size_t)NPIX * CC;

    hipLaunchKernelGGL(setup_kernel, dim3(20), dim3(256), 0, stream,
                       w1, b1, gamma, beta, bn_mean, bn_var, w2, b2,
                       w1b, w2bT, scalef, biasf, b2f);

    hipLaunchKernelGGL(kern_gen, dim3(NPIX / 64), dim3(256), 0, stream,
                       x, w1b, w2bT, scalef, biasf, b2f, kout);

    hipLaunchKernelGGL(invol2, dim3(NPIX * 4 / 256), dim3(256), 0, stream,
                       x, kout, out);
}

// Round 12
// 45.678 us; speedup vs baseline: 1.3512x; 1.3512x over previous
//
#include <hip/hip_runtime.h>

typedef unsigned int uint;
typedef unsigned short ushort_t;
typedef __attribute__((ext_vector_type(8))) short short8v;   // 8 bf16 (4 VGPRs)
typedef __attribute__((ext_vector_type(4))) float f32x4;

#define BATCH 8
#define HH 128
#define WW 128
#define CC 64
#define NPIX (BATCH * HH * WW)   // 131072
#define KK 9
#define BN_EPS 1e-3f

__device__ __forceinline__ uint f2bfbits(float f) {
    uint u = __float_as_uint(f);
    return (u + 0x7fffu + ((u >> 16) & 1u)) >> 16;   // RNE
}

// ---- setup: w1 -> bf16 [d][c]; w2 -> bf16 transposed [k][d]; fold BN ----
__global__ void setup_kernel(const float* __restrict__ w1,
                             const float* __restrict__ b1,
                             const float* __restrict__ gamma,
                             const float* __restrict__ beta,
                             const float* __restrict__ bn_mean,
                             const float* __restrict__ bn_var,
                             const float* __restrict__ w2,
                             const float* __restrict__ b2,
                             ushort_t* __restrict__ w1b,    // [64][64] bf16: w1b[d][c] = w1[c][d]
                             ushort_t* __restrict__ w2bT,   // [16][64] bf16: w2bT[k][d] = w2[d][k]
                             float* __restrict__ scalef,    // [64]
                             float* __restrict__ biasf,     // [64]
                             float* __restrict__ b2f)       // [9]
{
    int t = blockIdx.x * blockDim.x + threadIdx.x;
    int nt = gridDim.x * blockDim.x;
    for (int idx = t; idx < CC * CC; idx += nt) {
        int d = idx >> 6, c = idx & 63;
        w1b[idx] = (ushort_t)f2bfbits(w1[c * CC + d]);
    }
    for (int idx = t; idx < 16 * CC; idx += nt) {
        int k = idx >> 6, d = idx & 63;
        w2bT[idx] = (k < KK) ? (ushort_t)f2bfbits(w2[d * KK + k]) : (ushort_t)0;
    }
    if (t < CC) {
        float s = gamma[t] * rsqrtf(bn_var[t] + BN_EPS);
        scalef[t] = s;
        biasf[t] = (b1[t] - bn_mean[t]) * s + beta[t];
    }
    if (t < KK) b2f[t] = b2[t];
}

// ---- fused: stage + tap-prefetch -> barrier -> MFMA GEMMs -> involution ----
__global__ __launch_bounds__(256) void invol_fused(
    const float* __restrict__ x,
    const ushort_t* __restrict__ w1b,
    const ushort_t* __restrict__ w2bT,
    const float* __restrict__ scalef,
    const float* __restrict__ biasf,
    const float* __restrict__ b2f,
    float* __restrict__ out,     // [NPIX][64]
    float* __restrict__ kout)    // [NPIX][9]
{
    __shared__ ushort_t xB[64][72];        // staged x tile (bf16), 9.2 KB
    __shared__ ushort_t hL[4][16][72];     // per-wave h (bf16), 9.2 KB
    __shared__ float    kS[64][12];        // kern per pixel, 3 KB

    const int t = threadIdx.x;
    const int w = __builtin_amdgcn_readfirstlane(t >> 6);
    const int l = t & 63;
    const int lq = l >> 4, lr = l & 15;
    int bid = blockIdx.x;
    bid = (bid & 7) * 256 + (bid >> 3);    // XCD swizzle (2048 = 8*256, bijective)
    const int p0 = bid * 64;

    // invol thread identity (needed for prefetch)
    const int pxl = t >> 2;                // 0..63 — lies in wave w's own px range
    const int c0i = (t & 3) * 16;
    const int p = p0 + pxl;
    const int b = p >> 14;
    const int i = (p >> 7) & 127;          // uniform per block
    const int j = p & 127;

    // ---- phase 0: DENSE stage x -> bf16 LDS (1KB contiguous per instruction) ----
#pragma unroll
    for (int r = 0; r < 4; ++r) {
        int idx = t + r * 256;
        int px = idx >> 4, c4 = idx & 15;
        float4 v = *(const float4*)(x + (size_t)(p0 + px) * CC + c4 * 4);
        uint2 pk;
        pk.x = f2bfbits(v.x) | (f2bfbits(v.y) << 16);
        pk.y = f2bfbits(v.z) | (f2bfbits(v.w) << 16);
        *(uint2*)(&xB[px][c4 * 4]) = pk;
    }

    // ---- T14 prefetch: taps (-1,-1) and (-1,0) issued BEFORE the barrier ----
    float4 pf[8];
    {
        const int im1 = max(i - 1, 0);
        const int jm1 = max(j - 1, 0);
        const float* rowm = x + ((size_t)b * HH + im1) * WW * CC;
        const float4* a0 = (const float4*)(rowm + (size_t)jm1 * CC + c0i);
        const float4* a1 = (const float4*)(rowm + (size_t)j * CC + c0i);
        pf[0] = a0[0]; pf[1] = a0[1]; pf[2] = a0[2]; pf[3] = a0[3];
        pf[4] = a1[0]; pf[5] = a1[1]; pf[6] = a1[2]; pf[7] = a1[3];
    }
    __syncthreads();   // the ONLY barrier (drains stage + prefetch together)

    // ---- GEMM1: wave w owns px [w*16,w*16+16); A from LDS (r6/r11-proven recipe) ----
    {
        short8v af[2];
#pragma unroll
        for (int ks = 0; ks < 2; ++ks)
            af[ks] = *(const short8v*)(&xB[w * 16 + lr][ks * 32 + lq * 8]);

        f32x4 acc[4];
#pragma unroll
        for (int n = 0; n < 4; ++n) acc[n] = (f32x4){0.f, 0.f, 0.f, 0.f};
#pragma unroll
        for (int ks = 0; ks < 2; ++ks)
#pragma unroll
            for (int n = 0; n < 4; ++n) {
                short8v bf = *(const short8v*)(w1b + (n * 16 + lr) * CC + ks * 32 + lq * 8);
                acc[n] = __builtin_amdgcn_mfma_f32_16x16x32_bf16(af[ks], bf, acc[n], 0, 0, 0);
            }

        // epilogue: BN+ReLU -> bf16 -> hL (C layout: row=px=lq*4+r, col=d=n*16+lr)
#pragma unroll
        for (int n = 0; n < 4; ++n) {
            const int d = n * 16 + lr;
            const float s = scalef[d], bb = biasf[d];
#pragma unroll
            for (int r = 0; r < 4; ++r) {
                float hv = fmaxf(fmaf(acc[n][r], s, bb), 0.f);
                hL[w][lq * 4 + r][d] = (ushort_t)f2bfbits(hv);
            }
        }
    }
    // same-wave LDS handoff (compiler lgkmcnt; r9/r11-proven)

    // ---- GEMM2: kern = h @ w2 + b2 via MFMA (M=16, N=16 pad, K=64; r9 recipe) ----
    {
        f32x4 acc2 = (f32x4){0.f, 0.f, 0.f, 0.f};
#pragma unroll
        for (int ks = 0; ks < 2; ++ks) {
            short8v a2  = *(const short8v*)(&hL[w][lr][ks * 32 + lq * 8]);
            short8v b2v = *(const short8v*)(w2bT + lr * CC + ks * 32 + lq * 8);
            acc2 = __builtin_amdgcn_mfma_f32_16x16x32_bf16(a2, b2v, acc2, 0, 0, 0);
        }
        if (lr < KK) {
            const float bk = b2f[lr];
#pragma unroll
            for (int r = 0; r < 4; ++r)
                kS[w * 16 + lq * 4 + r][lr] = acc2[r] + bk;
        }
    }
    // same-wave handoff; dense kout drain: 36 float4 per wave (rows w*16..w*16+15)
    {
        float* kbase = kout + (size_t)(p0 + w * 16) * KK;
        if (l < 36) {
            float v[4];
#pragma unroll
            for (int e = 0; e < 4; ++e) {
                int f = l * 4 + e;
                v[e] = kS[w * 16 + f / KK][f % KK];
            }
            *(f32x4*)(kbase + l * 4) = (f32x4){v[0], v[1], v[2], v[3]};
        }
    }

    // ---- involution: thread = (pxl, 16-ch quarter); kern same-wave from kS ----
    float kern[KK];
#pragma unroll
    for (int k = 0; k < KK; ++k) kern[k] = kS[pxl][k];

    float4 accv[4];
#pragma unroll
    for (int f = 0; f < 4; ++f) accv[f] = make_float4(0.f, 0.f, 0.f, 0.f);

    // row -1: consume prefetched taps 0,1; fresh load tap 2
    if (i > 0) {
        float kv0 = (j > 0) ? kern[0] : 0.f;
        accv[0].x = fmaf(kv0, pf[0].x, accv[0].x); accv[0].y = fmaf(kv0, pf[0].y, accv[0].y);
        accv[0].z = fmaf(kv0, pf[0].z, accv[0].z); accv[0].w = fmaf(kv0, pf[0].w, accv[0].w);
        accv[1].x = fmaf(kv0, pf[1].x, accv[1].x); accv[1].y = fmaf(kv0, pf[1].y, accv[1].y);
        accv[1].z = fmaf(kv0, pf[1].z, accv[1].z); accv[1].w = fmaf(kv0, pf[1].w, accv[1].w);
        accv[2].x = fmaf(kv0, pf[2].x, accv[2].x); accv[2].y = fmaf(kv0, pf[2].y, accv[2].y);
        accv[2].z = fmaf(kv0, pf[2].z, accv[2].z); accv[2].w = fmaf(kv0, pf[2].w, accv[2].w);
        accv[3].x = fmaf(kv0, pf[3].x, accv[3].x); accv[3].y = fmaf(kv0, pf[3].y, accv[3].y);
        accv[3].z = fmaf(kv0, pf[3].z, accv[3].z); accv[3].w = fmaf(kv0, pf[3].w, accv[3].w);
        float kv1 = kern[1];
#pragma unroll
        for (int f = 0; f < 4; ++f) {
            accv[f].x = fmaf(kv1, pf[4 + f].x, accv[f].x);
            accv[f].y = fmaf(kv1, pf[4 + f].y, accv[f].y);
            accv[f].z = fmaf(kv1, pf[4 + f].z, accv[f].z);
            accv[f].w = fmaf(kv1, pf[4 + f].w, accv[f].w);
        }
        // tap 2: (-1,+1)
        {
            int jj = j + 1;
            bool valid = (jj < WW);
            float kv = valid ? kern[2] : 0.f;
            int jjc = min(jj, WW - 1);
            const float* rowm = x + ((size_t)b * HH + (i - 1)) * WW * CC;
            const float4* np = (const float4*)(rowm + (size_t)jjc * CC + c0i);
#pragma unroll
            for (int f = 0; f < 4; ++f) {
                float4 v = np[f];
                accv[f].x = fmaf(kv, v.x, accv[f].x);
                accv[f].y = fmaf(kv, v.y, accv[f].y);
                accv[f].z = fmaf(kv, v.z, accv[f].z);
                accv[f].w = fmaf(kv, v.w, accv[f].w);
            }
        }
    }

    // rows 0 and +1: fresh loads (r6-proven loop)
#pragma unroll
    for (int ti = 0; ti <= 1; ++ti) {
        int ii = i + ti;
        if (ii >= HH) continue;               // wave-uniform
        const float* rowp = x + ((size_t)b * HH + ii) * WW * CC;
#pragma unroll
        for (int tj = -1; tj <= 1; ++tj) {
            const int tap = (ti + 1) * 3 + (tj + 1);
            int jj = j + tj;
            bool valid = (jj >= 0) && (jj < WW);
            float kv = valid ? kern[tap] : 0.f;
            int jjc = min(max(jj, 0), WW - 1);
            const float4* np = (const float4*)(rowp + (size_t)jjc * CC + c0i);
#pragma unroll
            for (int f = 0; f < 4; ++f) {
                float4 v = np[f];
                accv[f].x = fmaf(kv, v.x, accv[f].x);
                accv[f].y = fmaf(kv, v.y, accv[f].y);
                accv[f].z = fmaf(kv, v.z, accv[f].z);
                accv[f].w = fmaf(kv, v.w, accv[f].w);
            }
        }
    }

    float4* op = (float4*)(out + (size_t)p * CC + c0i);
#pragma unroll
    for (int f = 0; f < 4; ++f) op[f] = accv[f];
}

extern "C" void kernel_launch(void* const* d_in, const int* in_sizes, int n_in,
                              void* d_out, int out_size, void* d_ws, size_t ws_size,
                              hipStream_t stream) {
    const float* x       = (const float*)d_in[0];
    const float* w1      = (const float*)d_in[1];
    const float* b1      = (const float*)d_in[2];
    const float* gamma   = (const float*)d_in[3];
    const float* beta    = (const float*)d_in[4];
    const float* bn_mean = (const float*)d_in[5];
    const float* bn_var  = (const float*)d_in[6];
    const float* w2      = (const float*)d_in[7];
    const float* b2      = (const float*)d_in[8];

    ushort_t* w1b  = (ushort_t*)d_ws;                // 4096 ush = 8192 B
    ushort_t* w2bT = w1b + CC * CC;                  // 1024 ush = 2048 B
    float* scalef  = (float*)(w2bT + 16 * CC);       // 64
    float* biasf   = scalef + CC;                    // 64
    float* b2f     = biasf + CC;                     // 9

    float* out  = (float*)d_out;
    float* kout = out + (size_t)NPIX * CC;

    hipLaunchKernelGGL(setup_kernel, dim3(20), dim3(256), 0, stream,
                       w1, b1, gamma, beta, bn_mean, bn_var, w2, b2,
                       w1b, w2bT, scalef, biasf, b2f);

    hipLaunchKernelGGL(invol_fused, dim3(NPIX / 64), dim3(256), 0, stream,
                       x, w1b, w2bT, scalef, biasf, b2f, out, kout);
}